// Round 13
// baseline (158.307 us; speedup 1.0000x reference)
//
#include <hip/hip_runtime.h>
#include <hip/hip_bf16.h>

// B=8, Ct=256, Cs=128, H=W=32, S=1024, E=256, nH=8, hd=32
typedef unsigned short u16;
typedef unsigned int u32;
typedef __attribute__((ext_vector_type(8))) short short8;
typedef __attribute__((ext_vector_type(4))) float f32x4;
typedef __attribute__((ext_vector_type(4))) unsigned short u16x4;
typedef __attribute__((ext_vector_type(4))) int i32x4;

static __device__ __forceinline__ u16 f2bf(float x) {
  __hip_bfloat16 b = __float2bfloat16(x);
  return *reinterpret_cast<u16*>(&b);
}
static __device__ __forceinline__ u32 fbits(float x) {
  union { float f; u32 u; } v; v.f = x; return v.u;
}
// pack two f32 -> two truncated bf16 in one dword
static __device__ __forceinline__ u32 pk_trunc(float lo, float hi) {
  return __builtin_amdgcn_perm(fbits(hi), fbits(lo), 0x07060302u);
}
// async global->LDS, 16B per lane; dest = lds base (wave-uniform) + lane*16
static __device__ __forceinline__ void gl2lds16(const u16* g, u16* l) {
  __builtin_amdgcn_global_load_lds(
      (const __attribute__((address_space(1))) void*)g,
      (__attribute__((address_space(3))) void*)l, 16, 0, 0);
}

// 1/sqrt(32) * log2(e)  (exp2-based softmax)
#define QSCALE2 (0.17677669529663687f * 1.4426950408889634f)

// ---------------------------------------------------------------------------
// Merged prep + register-transpose-cast + attn_out zero. (R12-exact)
// ---------------------------------------------------------------------------
__global__ __launch_bounds__(256) void prep_xpose(
    const float* __restrict__ in_proj_w, const float* __restrict__ in_proj_b,
    const float* __restrict__ kv_w, const float* __restrict__ fuse_w,
    const float* __restrict__ out_proj_w, const float* __restrict__ out_proj_b,
    const float* __restrict__ gamma, const float* __restrict__ beta,
    const float* __restrict__ mean, const float* __restrict__ var,
    const float* __restrict__ tgt, const float* __restrict__ src,
    u16* __restrict__ WqB, u16* __restrict__ WkvB, u16* __restrict__ M2B,
    float* __restrict__ qbias, float2* __restrict__ bnpk,
    u16* __restrict__ tgtT, u16* __restrict__ srcT,
    float* __restrict__ attn_out) {
  if (blockIdx.x >= 1537) {
    int i = (blockIdx.x - 1537) * 256 + threadIdx.x;
    attn_out[i] = 0.f;
    return;
  }
  if (blockIdx.x < 769) {
    int idx = blockIdx.x * 256 + threadIdx.x;
    if (idx < 65536) {
      WqB[idx] = f2bf(in_proj_w[idx] * QSCALE2);
    } else if (idx < 131072) {
      int i = idx - 65536;
      int m = i >> 7, c = i & 127;
      const float* wrow = in_proj_w + (size_t)(256 + m) * 256;
      float s = 0.f;
      for (int e2 = 0; e2 < 256; ++e2) s += wrow[e2] * kv_w[e2 * 128 + c];
      WkvB[i] = f2bf(s);
    } else if (idx < 196608) {
      int i = idx - 131072;
      int c = i >> 8, e2 = i & 255;
      float s = 0.f;
      for (int e = 0; e < 256; ++e)
        s += fuse_w[c * 256 + e] * out_proj_w[e * 256 + e2];
      M2B[i] = f2bf(s);
    } else if (idx < 196864) {
      int c = idx - 196608;
      float fbv = 0.f;
      for (int e = 0; e < 256; ++e) fbv += fuse_w[c * 256 + e] * out_proj_b[e];
      float inv = gamma[c] * rsqrtf(var[c] + 1e-5f);
      bnpk[c] = make_float2(inv, (fbv - mean[c]) * inv + beta[c]);
      qbias[c] = in_proj_b[c] * QSCALE2;
    }
    return;
  }
  // ---- xpose: register 4x4 transpose-cast ----
  int i0 = blockIdx.x - 769;
  int b = i0 / 96, rem = i0 % 96;
  int by = rem >> 4, sb = (rem & 15) * 64;
  const float* X;
  u16* XT;
  int C, cb;
  if (by < 4) {
    X = tgt + (size_t)b * 256 * 1024;
    XT = tgtT + (size_t)b * 1024 * 256;
    C = 256;
    cb = by * 64;
  } else {
    X = src + (size_t)b * 128 * 1024;
    XT = srcT + (size_t)b * 1024 * 128;
    C = 128;
    cb = (by - 4) * 64;
  }
  int t = threadIdx.x;
  int c = cb + (t >> 4) * 4;
  int s = sb + (t & 15) * 4;
  const float* Xp = X + (size_t)c * 1024 + s;
  float4 r0 = *(const float4*)(Xp);
  float4 r1 = *(const float4*)(Xp + 1024);
  float4 r2 = *(const float4*)(Xp + 2048);
  float4 r3 = *(const float4*)(Xp + 3072);
  u16* XTp = XT + (size_t)s * C + c;
  u16x4 o;
  o[0] = f2bf(r0.x); o[1] = f2bf(r1.x); o[2] = f2bf(r2.x); o[3] = f2bf(r3.x);
  *(u16x4*)(XTp) = o;
  o[0] = f2bf(r0.y); o[1] = f2bf(r1.y); o[2] = f2bf(r2.y); o[3] = f2bf(r3.y);
  *(u16x4*)(XTp + C) = o;
  o[0] = f2bf(r0.z); o[1] = f2bf(r1.z); o[2] = f2bf(r2.z); o[3] = f2bf(r3.z);
  *(u16x4*)(XTp + 2 * C) = o;
  o[0] = f2bf(r0.w); o[1] = f2bf(r1.w); o[2] = f2bf(r2.w); o[3] = f2bf(r3.w);
  *(u16x4*)(XTp + 3 * C) = o;
}

// ---------------------------------------------------------------------------
// QKV projection: 64m x 64n tiles for occupancy (grid 1536 = 6 blocks/CU).
// Same staging pattern (global_load_lds, unpadded 64B rows). LDS 8KB.
// ---------------------------------------------------------------------------
__global__ __launch_bounds__(256, 6) void qkv_gemm(
    const u16* __restrict__ tgtT, const u16* __restrict__ srcT,
    const u16* __restrict__ WqB, const u16* __restrict__ WkvB,
    const float* __restrict__ qbias, const float* __restrict__ bkv,
    u16* __restrict__ QB, u16* __restrict__ KB, u16* __restrict__ VB) {
  __shared__ __align__(16) u16 Wl[64 * 32];  // 4KB
  __shared__ __align__(16) u16 Xl[64 * 32];  // 4KB
  int b = blockIdx.z, my = blockIdx.y, n0 = blockIdx.x * 64;
  bool isQ = my < 4;
  int m0 = isQ ? my * 64 : (my - 4) * 64;
  int Kd = isQ ? 256 : 128;
  const u16* Wp = isQ ? WqB : WkvB;
  const u16* Xp = isQ ? tgtT + (size_t)b * 1024 * 256
                      : srcT + (size_t)b * 1024 * 128;
  int t = threadIdx.x, wave = t >> 6, lane = t & 63;
  int lq = lane & 15, quad = lane >> 4;
  int srow = t >> 2, sseg = t & 3;
  f32x4 acc[4];
#pragma unroll
  for (int mt = 0; mt < 4; ++mt) acc[mt] = (f32x4){0.f, 0.f, 0.f, 0.f};

  for (int k0 = 0; k0 < Kd; k0 += 32) {
    __syncthreads();
    gl2lds16(&Wp[(size_t)(m0 + srow) * Kd + k0 + sseg * 8], &Wl[wave * 512]);
    gl2lds16(&Xp[(size_t)(n0 + srow) * Kd + k0 + sseg * 8], &Xl[wave * 512]);
    __syncthreads();
    short8 bf = *(const short8*)&Xl[(wave * 16 + lq) * 32 + quad * 8];
    short8 af[4];
#pragma unroll
    for (int mt = 0; mt < 4; ++mt)
      af[mt] = *(const short8*)&Wl[(mt * 16 + lq) * 32 + quad * 8];
#pragma unroll
    for (int mt = 0; mt < 4; ++mt)
      acc[mt] = __builtin_amdgcn_mfma_f32_16x16x32_bf16(af[mt], bf, acc[mt], 0, 0, 0);
  }
  int n = n0 + wave * 16 + lq;
  if (isQ) {
#pragma unroll
    for (int mt = 0; mt < 4; ++mt) {
      int e = m0 + mt * 16 + quad * 4;
      f32x4 bi = *(const f32x4*)&qbias[e];
      int hh = e >> 5, d0 = e & 31;
      u16x4 pk;
#pragma unroll
      for (int r = 0; r < 4; ++r) pk[r] = f2bf(acc[mt][r] + bi[r]);
      *(u16x4*)&QB[((size_t)(b * 8 + hh) * 1024 + n) * 32 + d0] = pk;
    }
  } else {
#pragma unroll
    for (int mt = 0; mt < 4; ++mt) {
      int m = m0 + mt * 16 + quad * 4;
      f32x4 bi = *(const f32x4*)&bkv[m];
      if (m < 256) {
        int hh = m >> 5, d = m & 31;
        u16x4 pk;
#pragma unroll
        for (int r = 0; r < 4; ++r) pk[r] = f2bf(acc[mt][r] + bi[r]);
        *(u16x4*)&KB[((size_t)(b * 8 + hh) * 1024 + n) * 32 + d] = pk;
      } else {
        int e = m - 256;
#pragma unroll
        for (int r = 0; r < 4; ++r)
          VB[((size_t)b * 256 + e + r) * 1024 + n] = f2bf(acc[mt][r] + bi[r]);
      }
    }
  }
}

// ---------------------------------------------------------------------------
// Attention pass A (R12-exact): register-P transposed scores, 256-key chunks,
// XCD swizzle (idx = qt*64 + pair). QB (B,nH,S,hd).
// ---------------------------------------------------------------------------
__global__ __launch_bounds__(256, 4) void attn_passA(
    const u16* __restrict__ QB, const u16* __restrict__ KB,
    const u16* __restrict__ VB, u16* __restrict__ ctxB,
    float* __restrict__ linv_ws) {
  __shared__ __align__(16) u16 Klds[256 * 32];  // 16KB, linear rows
  __shared__ __align__(16) u16 Vlds[8 * 1056];  // 16.9KB
  int bidx = blockIdx.x;
  int pair = bidx & 63, q0 = (bidx >> 6) * 64;
  int b = pair >> 3, h = pair & 7;
  int t = threadIdx.x, wave = t >> 6, lane = t & 63;
  int lq = lane & 15, quad = lane >> 4;
  int srow = t >> 2, sseg = t & 3;

  const u16* Qb = QB + (size_t)pair * 1024 * 32;
  const u16* Kb = KB + (size_t)pair * 1024 * 32;
  const u16* Vb = VB + (size_t)(b * 256 + h * 32) * 1024;

  int myq = q0 + wave * 16 + lq;
  short8 qf = *(const short8*)(Qb + (size_t)myq * 32 + quad * 8);

  const f32x4 zf = (f32x4){0.f, 0.f, 0.f, 0.f};
  f32x4 O0 = zf, O1 = zf;
  float lsum = 0.f;
  int keyA = ((lq >> 2) << 3) | (lq & 3);

  for (int c0 = 0; c0 < 1024; c0 += 256) {
    __syncthreads();
#pragma unroll
    for (int i = 0; i < 4; ++i)
      gl2lds16(Kb + (size_t)(c0 + i * 64 + srow) * 32 + sseg * 8,
               &Klds[i * 2048 + wave * 512]);
#pragma unroll
    for (int i = 0; i < 2; ++i) {
      int g = wave * 2 + i;
#pragma unroll
      for (int j = 0; j < 2; ++j) {
        int d = g * 4 + j * 2 + (lane >> 5);
        gl2lds16(Vb + (size_t)d * 1024 + c0 + (lane & 31) * 8,
                 &Vlds[g * 1056 + j * 512]);
      }
    }
    __syncthreads();
#pragma unroll
    for (int pr = 0; pr < 8; ++pr) {
      short8 kf0 = *(const short8*)&Klds[(pr * 32 + keyA) * 32 + quad * 8];
      short8 kf1 = *(const short8*)&Klds[(pr * 32 + keyA + 4) * 32 + quad * 8];
      f32x4 s0 = __builtin_amdgcn_mfma_f32_16x16x32_bf16(kf0, qf, zf, 0, 0, 0);
      f32x4 s1 = __builtin_amdgcn_mfma_f32_16x16x32_bf16(kf1, qf, zf, 0, 0, 0);
      f32x4 e0, e1;
#pragma unroll
      for (int r = 0; r < 4; ++r) {
        e0[r] = exp2f(s0[r]);
        e1[r] = exp2f(s1[r]);
      }
      lsum += (e0[0] + e0[1]) + (e0[2] + e0[3]) +
              (e1[0] + e1[1]) + (e1[2] + e1[3]);
      i32x4 pi;
      pi[0] = (int)pk_trunc(e0[0], e0[1]);
      pi[1] = (int)pk_trunc(e0[2], e0[3]);
      pi[2] = (int)pk_trunc(e1[0], e1[1]);
      pi[3] = (int)pk_trunc(e1[2], e1[3]);
      short8 pf = *(short8*)&pi;
      short8 vf0 = *(const short8*)&Vlds[(lq >> 2) * 1056 + (lq & 3) * 256 +
                                         pr * 32 + quad * 8];
      short8 vf1 = *(const short8*)&Vlds[(4 + (lq >> 2)) * 1056 + (lq & 3) * 256 +
                                         pr * 32 + quad * 8];
      O0 = __builtin_amdgcn_mfma_f32_16x16x32_bf16(vf0, pf, O0, 0, 0, 0);
      O1 = __builtin_amdgcn_mfma_f32_16x16x32_bf16(vf1, pf, O1, 0, 0, 0);
    }
  }

  lsum += __shfl_xor(lsum, 16);
  lsum += __shfl_xor(lsum, 32);
  float linv = 1.f / lsum;

  u16x4 pk0, pk1;
#pragma unroll
  for (int r = 0; r < 4; ++r) {
    pk0[r] = f2bf(O0[r] * linv);
    pk1[r] = f2bf(O1[r] * linv);
  }
  u16* crow = ctxB + ((size_t)b * 1024 + myq) * 256 + h * 32 + quad * 4;
  *(u16x4*)crow = pk0;
  *(u16x4*)(crow + 16) = pk1;
  if (quad == 0) linv_ws[(size_t)pair * 1024 + myq] = linv;
}

// ---------------------------------------------------------------------------
// Colsum, 32-key blocks for full occupancy: grid 2048 = 8 blocks/CU, LDS 2KB.
// K staged once (waves 0-1), register K-frags, 16 query-group iterations.
// ---------------------------------------------------------------------------
__global__ __launch_bounds__(256, 8) void colsum_kernel(
    const u16* __restrict__ QB, const u16* __restrict__ KB,
    const float* __restrict__ linv_ws, float* __restrict__ attn_out) {
  __shared__ __align__(16) u16 Klds[32 * 32];  // 2KB
  int bidx = blockIdx.x;
  int pair = bidx & 63, k0 = (bidx >> 6) * 32;
  int b = pair >> 3;
  int t = threadIdx.x, wave = t >> 6, lane = t & 63;
  int lq = lane & 15, quad = lane >> 4;

  const u16* Qb = QB + (size_t)pair * 1024 * 32;
  const u16* Kb = KB + (size_t)pair * 1024 * 32;
  const float* lvp = linv_ws + (size_t)pair * 1024;

  if (wave < 2)
    gl2lds16(Kb + (size_t)(k0 + wave * 16 + (lane >> 2)) * 32 + (lane & 3) * 8,
             &Klds[wave * 512]);
  __syncthreads();

  short8 kf[2];
#pragma unroll
  for (int nt = 0; nt < 2; ++nt)
    kf[nt] = *(const short8*)&Klds[(nt * 16 + lq) * 32 + quad * 8];

  const f32x4 zf = (f32x4){0.f, 0.f, 0.f, 0.f};
  float cs[2] = {0.f, 0.f};
  for (int g = 0; g < 16; ++g) {
    int qg = g * 64 + wave * 16;
    short8 qf = *(const short8*)(Qb + (size_t)(qg + lq) * 32 + quad * 8);
    f32x4 lv = *(const f32x4*)&lvp[qg + quad * 4];
#pragma unroll
    for (int nt = 0; nt < 2; ++nt) {
      f32x4 s = __builtin_amdgcn_mfma_f32_16x16x32_bf16(qf, kf[nt], zf, 0, 0, 0);
      cs[nt] += exp2f(s[0]) * lv[0] + exp2f(s[1]) * lv[1] +
                exp2f(s[2]) * lv[2] + exp2f(s[3]) * lv[3];
    }
  }
#pragma unroll
  for (int nt = 0; nt < 2; ++nt) {
    float v = cs[nt];
    v += __shfl_xor(v, 16);
    v += __shfl_xor(v, 32);
    if (quad == 0)
      atomicAdd(&attn_out[b * 1024 + k0 + nt * 16 + lq], v * (1.f / 8192.f));
  }
}

// ---------------------------------------------------------------------------
// Fused out GEMM + BN + SiLU + residual: 64c x 32s tiles, grid (32,4,8)=1024
// (4 blocks/CU vs 2 before). Waves split (c-half, s-half). LDS 6KB.
// ---------------------------------------------------------------------------
__global__ __launch_bounds__(256, 4) void fused_out(
    const u16* __restrict__ M2B, const u16* __restrict__ ctxB,
    const float* __restrict__ tgt, const float2* __restrict__ bnpk,
    float* __restrict__ y) {
  __shared__ __align__(16) u16 Al[64 * 32];  // 4KB
  __shared__ __align__(16) u16 Bl[32 * 32];  // 2KB
  int b = blockIdx.z, c0 = blockIdx.y * 64, s0 = blockIdx.x * 32;
  int t = threadIdx.x, wave = t >> 6, lane = t & 63;
  int lq = lane & 15, quad = lane >> 4;
  int srow = t >> 2, sseg = t & 3;
  int sh = wave & 1, ch = wave >> 1;
  f32x4 acc[2];
  acc[0] = (f32x4){0.f, 0.f, 0.f, 0.f};
  acc[1] = (f32x4){0.f, 0.f, 0.f, 0.f};

  for (int k0 = 0; k0 < 256; k0 += 32) {
    __syncthreads();
    gl2lds16(&M2B[(size_t)(c0 + srow) * 256 + k0 + sseg * 8], &Al[wave * 512]);
    if (wave < 2)
      gl2lds16(&ctxB[((size_t)b * 1024 + s0 + wave * 16 + (lane >> 2)) * 256 +
                     k0 + (lane & 3) * 8],
               &Bl[wave * 512]);
    __syncthreads();
    short8 bf = *(const short8*)&Bl[(sh * 16 + lq) * 32 + quad * 8];
    short8 af[2];
#pragma unroll
    for (int mt = 0; mt < 2; ++mt)
      af[mt] = *(const short8*)&Al[(ch * 32 + mt * 16 + lq) * 32 + quad * 8];
#pragma unroll
    for (int mt = 0; mt < 2; ++mt)
      acc[mt] = __builtin_amdgcn_mfma_f32_16x16x32_bf16(af[mt], bf, acc[mt], 0, 0, 0);
  }
  int s = s0 + sh * 16 + lq;
#pragma unroll
  for (int mt = 0; mt < 2; ++mt) {
#pragma unroll
    for (int r = 0; r < 4; ++r) {
      int c = c0 + ch * 32 + mt * 16 + quad * 4 + r;
      float2 p = bnpk[c];
      float bn = acc[mt][r] * p.x + p.y;
      float sig = 1.f / (1.f + __expf(-bn));
      size_t idx = ((size_t)b * 256 + c) * 1024 + s;
      y[idx] = tgt[idx] + bn * sig;
    }
  }
}

// ---------------------------------------------------------------------------
extern "C" void kernel_launch(void* const* d_in, const int* in_sizes, int n_in,
                              void* d_out, int out_size, void* d_ws, size_t ws_size,
                              hipStream_t stream) {
  const float* tgt = (const float*)d_in[0];
  const float* src = (const float*)d_in[1];
  const float* kv_w = (const float*)d_in[2];
  const float* in_proj_w = (const float*)d_in[3];
  const float* in_proj_b = (const float*)d_in[4];
  const float* out_proj_w = (const float*)d_in[5];
  const float* out_proj_b = (const float*)d_in[6];
  const float* fuse_w = (const float*)d_in[7];
  const float* bn_gamma = (const float*)d_in[8];
  const float* bn_beta = (const float*)d_in[9];
  const float* bn_mean = (const float*)d_in[10];
  const float* bn_var = (const float*)d_in[11];

  char* W = (char*)d_ws;
  u16* WqB = (u16*)W;                      // 128KB
  u16* WkvB = (u16*)(W + 131072);          // 128KB
  u16* M2B = (u16*)(W + 262144);           // 128KB
  float* qbias = (float*)(W + 393216);     // 1KB
  float2* bnpk = (float2*)(W + 394240);    // 2KB
  u16* tgtT = (u16*)(W + 397312);          // 4MB (B,S,256) bf16
  u16* srcT = tgtT + 2097152;              // 2MB (B,S,128) bf16
  u16* QB = srcT + 1048576;                // 4MB (B,nH,S,hd)
  u16* KB = QB + 2097152;                  // 4MB (B,nH,S,hd)
  u16* VB = KB + 2097152;                  // 4MB (B,E,S)
  u16* ctxB = VB + 2097152;                // 4MB (B,S,E)
  float* linv_ws = (float*)(ctxB + 2097152);  // 256KB (B,nH,S)

  float* y = (float*)d_out;
  float* attn_out = y + 2097152;

  prep_xpose<<<1569, 256, 0, stream>>>(in_proj_w, in_proj_b, kv_w, fuse_w,
                                       out_proj_w, out_proj_b, bn_gamma, bn_beta,
                                       bn_mean, bn_var, tgt, src,
                                       WqB, WkvB, M2B, qbias, bnpk, tgtT, srcT,
                                       attn_out);
  qkv_gemm<<<dim3(16, 12, 8), 256, 0, stream>>>(tgtT, srcT, WqB, WkvB, qbias,
                                                in_proj_b + 256, QB, KB, VB);
  attn_passA<<<1024, 256, 0, stream>>>(QB, KB, VB, ctxB, linv_ws);
  colsum_kernel<<<2048, 256, 0, stream>>>(QB, KB, linv_ws, attn_out);
  fused_out<<<dim3(32, 4, 8), 256, 0, stream>>>(M2B, ctxB, tgt, bnpk, y);
}